// Round 11
// baseline (700.084 us; speedup 1.0000x reference)
//
#include <hip/hip_runtime.h>
#include <hip/hip_bf16.h>
#include <cstdint>
#include <cstddef>

#define N_NODES 50000
#define DIM 512
#define N_EDGES 1600000
#define NT 25           // column tiles of 2048 nodes (2 MB of bf16 y per tile)
#define NB (N_NODES * NT)
#define GPANELS 391     // ceil(50000/128) row panels in gemm
#define NSHAD 8         // shadow copies for reduce atomics

typedef __bf16 bf16;
typedef __bf16 bf16x8 __attribute__((ext_vector_type(8)));
typedef __bf16 bf16x4 __attribute__((ext_vector_type(4)));
typedef float floatx4 __attribute__((ext_vector_type(4)));

// ---------------- prep: cast x & w to bf16, zero cnt + stat buffers (1 dispatch) ----
__global__ void prep_kernel(const float* __restrict__ x, bf16* __restrict__ xb,
                            const float* __restrict__ w, bf16* __restrict__ wb,
                            int4* __restrict__ cnt4, float4* __restrict__ stats4,
                            int n4x, int n4w) {
    int i = blockIdx.x * blockDim.x + threadIdx.x;
    if (i < n4x) {
        float4 v = reinterpret_cast<const float4*>(x)[i];
        bf16x4 o;
        o[0] = (bf16)v.x; o[1] = (bf16)v.y; o[2] = (bf16)v.z; o[3] = (bf16)v.w;
        reinterpret_cast<bf16x4*>(xb)[i] = o;
    }
    if (i < n4w) {
        float4 v = reinterpret_cast<const float4*>(w)[i];
        bf16x4 o;
        o[0] = (bf16)v.x; o[1] = (bf16)v.y; o[2] = (bf16)v.z; o[3] = (bf16)v.w;
        reinterpret_cast<bf16x4*>(wb)[i] = o;
    }
    if (i < NB / 4) cnt4[i] = make_int4(0, 0, 0, 0);
    if (i < 1026) stats4[i] = make_float4(0.f, 0.f, 0.f, 0.f);  // colsumS[4096]+totsqS[8]
}

// ---------------- bucketed CSR build: key = row*NT + (col>>11) ----------------
__global__ void hist_kernel(const int* __restrict__ rows, const int* __restrict__ cols,
                            int* __restrict__ cnt, int E) {
    int i = blockIdx.x * blockDim.x + threadIdx.x;
    if (i < E) {
        int key = rows[i] * NT + (cols[i] >> 11);
        atomicAdd(&cnt[key], 1);
    }
}

// scanA: wave-shuffle scan (verified R10)
__global__ __launch_bounds__(1024) void scanA_kernel(const int* __restrict__ cnt,
                                                     int* __restrict__ row_start,
                                                     int* __restrict__ blksum, int n) {
    const int t = threadIdx.x;
    int i = blockIdx.x * 1024 + t;
    int v = (i < n) ? cnt[i] : 0;
    int s = v;
#pragma unroll
    for (int off = 1; off < 64; off <<= 1) {
        int u = __shfl_up(s, off, 64);
        if ((t & 63) >= off) s += u;
    }
    __shared__ int wsum[16];
    if ((t & 63) == 63) wsum[t >> 6] = s;
    __syncthreads();
    if (t < 16) {
        int w = wsum[t];
#pragma unroll
        for (int off = 1; off < 16; off <<= 1) {
            int u = __shfl_up(w, off, 16);
            if (t >= off) w += u;
        }
        wsum[t] = w;
    }
    __syncthreads();
    int base = (t >= 64) ? wsum[(t >> 6) - 1] : 0;
    int incl = s + base;
    if (i < n) row_start[i] = incl - v;
    if (t == 1023) blksum[blockIdx.x] = incl;
}

__global__ __launch_bounds__(1024) void scanB_kernel(const int* __restrict__ blksum,
                                                     int* __restrict__ blkoff, int nb) {
    __shared__ int s[1024];
    const int t = threadIdx.x;
    const int base = t * 2;
    int a = (base < nb) ? blksum[base] : 0;
    int b = (base + 1 < nb) ? blksum[base + 1] : 0;
    s[t] = a + b;
    __syncthreads();
    for (int off = 1; off < 1024; off <<= 1) {
        int u = (t >= off) ? s[t - off] : 0;
        __syncthreads();
        s[t] += u;
        __syncthreads();
    }
    int excl = (t == 0) ? 0 : s[t - 1];
    if (base < nb) blkoff[base] = excl;
    if (base + 1 < nb) blkoff[base + 1] = excl + a;
}

__global__ __launch_bounds__(1024) void scanC_kernel(int* __restrict__ row_start,
                                                     const int* __restrict__ blkoff,
                                                     int* __restrict__ cursor, int n) {
    int i = blockIdx.x * 1024 + threadIdx.x;
    if (i >= n) return;
    int v = row_start[i] + blkoff[i >> 10];
    row_start[i] = v;
    cursor[i] = v;
    if (i == n - 1) row_start[n] = N_EDGES;
}

__global__ void scatter_kernel(const int* __restrict__ rows, const int* __restrict__ cols,
                               const float* __restrict__ vals, int* __restrict__ cursor,
                               int2* __restrict__ ecv, int E) {
    int i = blockIdx.x * blockDim.x + threadIdx.x;
    if (i >= E) return;
    int c = cols[i];
    int key = rows[i] * NT + (c >> 11);
    int p = atomicAdd(&cursor[key], 1);
    ecv[p] = make_int2(c, __float_as_int(vals[i]));
}

// ---------------- GEMM v11: 2-phase double-buffered pipeline ----------------
// Old loop: {stage -> barrier -> consume -> barrier} x16 = 32 barriers, no overlap.
// New: T3-lite 2-phase: per K-step {STAGE(next buf) ; consume current ; 1 barrier}.
// Staging flight time hides under ds_read+MFMA; 17 barriers total. LDS 2x16KB=32KB.
__global__ __launch_bounds__(256) void gemm_kernel(const bf16* __restrict__ A,
                                                   const bf16* __restrict__ B,
                                                   bf16* __restrict__ C) {
    __shared__ bf16 lA[2][128 * 32];
    __shared__ bf16 lB[2][128 * 32];
    const int d = blockIdx.x;
    const int p = (d & 7) + ((d >> 5) << 3);  // row panel (XCD-chunked swizzle)
    const int c = (d >> 3) & 3;               // col tile
    if (p >= GPANELS) return;
    const int t = threadIdx.x;
    const int wave = t >> 6;
    const int lane = t & 63;
    const int rowBase = p * 128;
    const int colBase = c * 128;
    const int wm = (wave >> 1) * 64;
    const int wn = (wave & 1) * 64;
    floatx4 acc[4][4] = {};

    const int r_a = t >> 2;       // 0..63 (tile row, first half)
    const int kk = (t & 3) * 8;   // k offset within 32-chunk
    const int l15 = lane & 15;
    const int koff = (lane >> 4) * 8;

    int arow0 = rowBase + r_a;
    if (arow0 > N_NODES - 1) arow0 = N_NODES - 1;
    int arow1 = rowBase + r_a + 64;
    if (arow1 > N_NODES - 1) arow1 = N_NODES - 1;
    const bf16* gA0 = A + (size_t)arow0 * DIM + kk;
    const bf16* gA1 = A + (size_t)arow1 * DIM + kk;
    const bf16* gB0 = B + (size_t)(colBase + r_a) * DIM + kk;
    const bf16* gB1 = B + (size_t)(colBase + r_a + 64) * DIM + kk;

    auto STAGE = [&](int b, int kc) {
        const int ko = kc * 32;
        __builtin_amdgcn_global_load_lds(
            (const __attribute__((address_space(1))) void*)(gA0 + ko),
            (__attribute__((address_space(3))) void*)(&lA[b][wave * 512]), 16, 0, 0);
        __builtin_amdgcn_global_load_lds(
            (const __attribute__((address_space(1))) void*)(gA1 + ko),
            (__attribute__((address_space(3))) void*)(&lA[b][wave * 512 + 2048]), 16, 0, 0);
        __builtin_amdgcn_global_load_lds(
            (const __attribute__((address_space(1))) void*)(gB0 + ko),
            (__attribute__((address_space(3))) void*)(&lB[b][wave * 512]), 16, 0, 0);
        __builtin_amdgcn_global_load_lds(
            (const __attribute__((address_space(1))) void*)(gB1 + ko),
            (__attribute__((address_space(3))) void*)(&lB[b][wave * 512 + 2048]), 16, 0, 0);
    };

    STAGE(0, 0);
    __syncthreads();
#pragma unroll
    for (int s = 0; s < 16; s++) {
        if (s + 1 < 16) STAGE((s + 1) & 1, s + 1);
        const int b = s & 1;
        bf16x8 af[4], bfr[4];
#pragma unroll
        for (int i = 0; i < 4; i++)
            af[i] = *reinterpret_cast<const bf16x8*>(&lA[b][(wm + i * 16 + l15) * 32 + koff]);
#pragma unroll
        for (int j = 0; j < 4; j++)
            bfr[j] = *reinterpret_cast<const bf16x8*>(&lB[b][(wn + j * 16 + l15) * 32 + koff]);
#pragma unroll
        for (int i = 0; i < 4; i++)
#pragma unroll
            for (int j = 0; j < 4; j++)
                acc[i][j] = __builtin_amdgcn_mfma_f32_16x16x32_bf16(af[i], bfr[j], acc[i][j], 0, 0, 0);
        __syncthreads();  // drains staging (vmcnt0) + guards buffer reuse
    }
    // epilogue: D row = (lane>>4)*4+reg (m), col = lane&15 (n)
    const int rquad = (lane >> 4) * 4;
#pragma unroll
    for (int i = 0; i < 4; i++) {
#pragma unroll
        for (int reg = 0; reg < 4; reg++) {
            int gr = rowBase + wm + i * 16 + rquad + reg;
            if (gr >= N_NODES) continue;
#pragma unroll
            for (int j = 0; j < 4; j++) {
                int gc = colBase + wn + j * 16 + l15;
                C[(size_t)gr * DIM + gc] = (bf16)acc[i][j][reg];
            }
        }
    }
}

// ---------------- SpMM (v1, measured best ~228us) ----------------
__device__ __forceinline__ float blo(uint32_t w) { return __uint_as_float(w << 16); }
__device__ __forceinline__ float bhi(uint32_t w) { return __uint_as_float(w & 0xffff0000u); }

__device__ __forceinline__ void fmac8(float* acc, float v, const uint4& w) {
    acc[0] += v * blo(w.x); acc[1] += v * bhi(w.x);
    acc[2] += v * blo(w.y); acc[3] += v * bhi(w.y);
    acc[4] += v * blo(w.z); acc[5] += v * bhi(w.z);
    acc[6] += v * blo(w.w); acc[7] += v * bhi(w.w);
}

__global__ __launch_bounds__(256) void spmm_kernel(const int* __restrict__ row_start,
                                                   const int2* __restrict__ ecv,
                                                   const bf16* __restrict__ y,
                                                   float* __restrict__ y2) {
    const int wave = threadIdx.x >> 6;
    const int lane = threadIdx.x & 63;
    const int r = blockIdx.x * 4 + wave;  // grid = 12500 exactly -> r < 50000
    const int s = row_start[r * NT];
    const int e = row_start[(r + 1) * NT];
    float acc[8] = {0.f, 0.f, 0.f, 0.f, 0.f, 0.f, 0.f, 0.f};
    const uint32_t* yb = reinterpret_cast<const uint32_t*>(y);

    int i = s;
    for (; i + 3 < e; i += 4) {
        int2 e0 = ecv[i], e1 = ecv[i + 1], e2 = ecv[i + 2], e3 = ecv[i + 3];
        uint4 w0 = *reinterpret_cast<const uint4*>(yb + (size_t)e0.x * 256 + lane * 4);
        uint4 w1 = *reinterpret_cast<const uint4*>(yb + (size_t)e1.x * 256 + lane * 4);
        uint4 w2 = *reinterpret_cast<const uint4*>(yb + (size_t)e2.x * 256 + lane * 4);
        uint4 w3 = *reinterpret_cast<const uint4*>(yb + (size_t)e3.x * 256 + lane * 4);
        fmac8(acc, __int_as_float(e0.y), w0);
        fmac8(acc, __int_as_float(e1.y), w1);
        fmac8(acc, __int_as_float(e2.y), w2);
        fmac8(acc, __int_as_float(e3.y), w3);
    }
    for (; i < e; i++) {
        int2 e0 = ecv[i];
        uint4 w0 = *reinterpret_cast<const uint4*>(yb + (size_t)e0.x * 256 + lane * 4);
        fmac8(acc, __int_as_float(e0.y), w0);
    }
    float4* out = reinterpret_cast<float4*>(y2 + (size_t)r * DIM + lane * 8);
    out[0] = make_float4(acc[0], acc[1], acc[2], acc[3]);
    out[1] = make_float4(acc[4], acc[5], acc[6], acc[7]);
}

// ---------------- reduction: 16-row chunks, 16 loads in flight (R10, ~30us) --------
#define RED_GRID 512
#define RED_CHUNK 16
__global__ __launch_bounds__(256) void reduce_kernel(const float* __restrict__ y2,
                                                     float* __restrict__ colsumS,
                                                     float* __restrict__ totsqS) {
    const int t = threadIdx.x;
    const int d2 = t * 2;
    float c0 = 0.f, c1 = 0.f, sq = 0.f;
    for (int r0 = blockIdx.x * RED_CHUNK; r0 < N_NODES; r0 += RED_GRID * RED_CHUNK) {
        float2 v[RED_CHUNK];
#pragma unroll
        for (int j = 0; j < RED_CHUNK; j++) {
            int r = r0 + j;
            v[j] = (r < N_NODES)
                       ? *reinterpret_cast<const float2*>(y2 + (size_t)r * DIM + d2)
                       : make_float2(0.f, 0.f);
        }
#pragma unroll
        for (int j = 0; j < RED_CHUNK; j++) {
            c0 += v[j].x;
            c1 += v[j].y;
            sq += v[j].x * v[j].x + v[j].y * v[j].y;
        }
    }
    const int sh = blockIdx.x & (NSHAD - 1);
    atomicAdd(&colsumS[sh * DIM + d2], c0);
    atomicAdd(&colsumS[sh * DIM + d2 + 1], c1);
    __shared__ float ssq[256];
    ssq[t] = sq;
    __syncthreads();
    for (int off = 128; off > 0; off >>= 1) {
        if (t < off) ssq[t] += ssq[t + off];
        __syncthreads();
    }
    if (t == 0) atomicAdd(&totsqS[sh], ssq[0]);
}

__global__ void scalar_kernel(const float* __restrict__ colsumS, const float* __restrict__ totsqS,
                              const float* __restrict__ scale, float* __restrict__ sfac,
                              float* __restrict__ colsum) {
    __shared__ float sm[512];
    const int t = threadIdx.x;
    float s = 0.f;
#pragma unroll
    for (int c = 0; c < NSHAD; c++) s += colsumS[c * DIM + t];
    colsum[t] = s;
    float mu = s * (1.0f / N_NODES);
    sm[t] = mu * mu;
    __syncthreads();
    for (int off = 256; off > 0; off >>= 1) {
        if (t < off) sm[t] += sm[t + off];
        __syncthreads();
    }
    if (t == 0) {
        float tq = 0.f;
#pragma unroll
        for (int c = 0; c < NSHAD; c++) tq += totsqS[c];
        float var = tq * (1.0f / N_NODES) - sm[0];
        sfac[0] = rsqrtf(var) * (1.0f + scale[0]) * sqrtf((float)DIM);
    }
}

// ---------------- final: out = relu((y2 - mu) * s) + x  (in place on d_out) ----------------
__global__ void final_kernel(float* __restrict__ y2, const float* __restrict__ x,
                             const float* __restrict__ colsum, const float* __restrict__ sfac,
                             int n4) {
    int i = blockIdx.x * blockDim.x + threadIdx.x;
    if (i >= n4) return;
    const float invN = 1.0f / N_NODES;
    float4 v = reinterpret_cast<float4*>(y2)[i];
    float4 xv = reinterpret_cast<const float4*>(x)[i];
    float4 mu = reinterpret_cast<const float4*>(colsum)[i & 127];
    float s = sfac[0];
    v.x = fmaxf((v.x - mu.x * invN) * s, 0.0f) + xv.x;
    v.y = fmaxf((v.y - mu.y * invN) * s, 0.0f) + xv.y;
    v.z = fmaxf((v.z - mu.z * invN) * s, 0.0f) + xv.z;
    v.w = fmaxf((v.w - mu.w * invN) * s, 0.0f) + xv.w;
    reinterpret_cast<float4*>(y2)[i] = v;
}

extern "C" void kernel_launch(void* const* d_in, const int* in_sizes, int n_in,
                              void* d_out, int out_size, void* d_ws, size_t ws_size,
                              hipStream_t stream) {
    const float* x        = (const float*)d_in[0];
    const int*   adj_rows = (const int*)d_in[1];
    const int*   adj_cols = (const int*)d_in[2];
    const float* adj_vals = (const float*)d_in[3];
    const float* weight   = (const float*)d_in[4];
    const float* scale    = (const float*)d_in[5];
    float* out = (float*)d_out;  // doubles as y2 buffer

    char* ws = (char*)d_ws;
    size_t off = 0;
    auto alloc = [&](size_t b) {
        char* p = ws + off;
        off += (b + 255) & ~(size_t)255;
        return p;
    };
    const int nblk = (NB + 1023) / 1024;  // 1221
    bf16*  xb        = (bf16*)alloc((size_t)N_NODES * DIM * 2);   // 51.2 MB
    int2*  ecv       = (int2*)xb;  // ALIAS: gemm (reader of xb) completes before scatter writes
    bf16*  Wb        = (bf16*)alloc((size_t)DIM * DIM * 2);       // 0.5 MB
    bf16*  y         = (bf16*)alloc((size_t)N_NODES * DIM * 2);   // 51.2 MB
    int*   cnt       = (int*)alloc((size_t)NB * 4);               // 5 MB
    int*   cursor    = cnt;        // ALIAS: cnt dead after scanA; cursor born in scanC
    int*   row_start = (int*)alloc((size_t)(NB + 1) * 4);         // 5 MB
    int*   blksum    = (int*)alloc((size_t)nblk * 4);
    int*   blkoff    = (int*)alloc((size_t)nblk * 4);
    float* colsumS   = (float*)alloc((size_t)NSHAD * DIM * 4);    // 16 KB (totsqS contiguous)
    float* totsqS    = (float*)alloc((size_t)NSHAD * 4);
    float* colsum    = (float*)alloc(512 * 4);
    float* sfac      = (float*)alloc(4);
    (void)ws_size; (void)in_sizes; (void)n_in; (void)out_size;

    const int n4x = N_NODES * DIM / 4;  // 6,400,000
    const int n4w = DIM * DIM / 4;      // 65,536

    // one dispatch: casts + cnt zero + stats zero (replaces 2 casts + 2 memsets)
    prep_kernel<<<(n4x + 255) / 256, 256, 0, stream>>>(x, xb, weight, Wb,
                                                       (int4*)cnt, (float4*)colsumS,
                                                       n4x, n4w);

    // GEMM first: frees xb so ecv can alias it.
    gemm_kernel<<<1568, 256, 0, stream>>>(xb, Wb, y);

    hist_kernel<<<(N_EDGES + 255) / 256, 256, 0, stream>>>(adj_rows, adj_cols, cnt, N_EDGES);
    scanA_kernel<<<nblk, 1024, 0, stream>>>(cnt, row_start, blksum, NB);
    scanB_kernel<<<1, 1024, 0, stream>>>(blksum, blkoff, nblk);
    scanC_kernel<<<nblk, 1024, 0, stream>>>(row_start, blkoff, cursor, NB);
    scatter_kernel<<<(N_EDGES + 255) / 256, 256, 0, stream>>>(adj_rows, adj_cols, adj_vals,
                                                              cursor, ecv, N_EDGES);

    spmm_kernel<<<N_NODES / 4, 256, 0, stream>>>(row_start, ecv, y, out);

    reduce_kernel<<<RED_GRID, 256, 0, stream>>>(out, colsumS, totsqS);
    scalar_kernel<<<1, 512, 0, stream>>>(colsumS, totsqS, scale, sfac, colsum);
    final_kernel<<<(n4x + 255) / 256, 256, 0, stream>>>(out, x, colsum, sfac, n4x);
}